// Round 1
// baseline (1754.924 us; speedup 1.0000x reference)
//
#include <hip/hip_runtime.h>
#include <math.h>

#define N 50000
#define E 800000
#define HID 64
#define OUTC 32
#define KCHEB 10
#define BT 20

// ---------------- degree count ----------------
__global__ void count_deg(const int* __restrict__ row, int* __restrict__ deg) {
    int e = blockIdx.x * blockDim.x + threadIdx.x;
    if (e < E) atomicAdd(&deg[row[e]], 1);
}

// ---------------- single-block exclusive scan over deg -> rowptr ----------------
__global__ __launch_bounds__(1024) void scan_deg(const int* __restrict__ deg, int* __restrict__ rowptr) {
    __shared__ int part[1024];
    int t = threadIdx.x;
    const int C = (N + 1023) / 1024;  // 49
    int begin = t * C;
    int end = begin + C; if (end > N) end = N;
    int s = 0;
    if (begin < N) for (int i = begin; i < end; i++) s += deg[i];
    part[t] = s;
    __syncthreads();
    // inclusive Hillis-Steele scan over 1024 partials
    for (int ofs = 1; ofs < 1024; ofs <<= 1) {
        int v = (t >= ofs) ? part[t - ofs] : 0;
        __syncthreads();
        part[t] += v;
        __syncthreads();
    }
    int run = (t == 0) ? 0 : part[t - 1];
    if (begin < N) {
        for (int i = begin; i < end; i++) { rowptr[i] = run; run += deg[i]; }
    }
    if (t == 1023) rowptr[N] = part[1023];
}

// ---------------- dinv from rowptr diffs ----------------
__global__ void compute_dinv(const int* __restrict__ rowptr, float* __restrict__ dinv) {
    int r = blockIdx.x * blockDim.x + threadIdx.x;
    if (r < N) {
        int d = rowptr[r + 1] - rowptr[r];
        dinv[r] = (d > 0) ? (1.0f / sqrtf((float)d)) : 0.0f;
    }
}

// ---------------- Chebyshev/Bessel coefficients ----------------
__global__ void compute_coeffs(const float* __restrict__ tptr, float* __restrict__ coeffs) {
    int v = threadIdx.x;
    if (v < KCHEB) {
        float t = tptr[0];
        float lt = logf(0.5f * t);
        float s = 0.f;
        for (int m = 0; m < BT; m++) {
            float lg = lgammaf((float)m + 1.0f) + lgammaf((float)(m + v) + 1.0f);
            s += expf((2.0f * m + (float)v) * lt - lg);
        }
        float c;
        if (v == 0) c = s;
        else c = ((v & 1) == 0) ? 2.0f * s : -2.0f * s;
        coeffs[v] = c;
    }
}

// ---------------- CSR fill (counting sort by row) ----------------
__global__ void fill_csr(const int* __restrict__ row, const int* __restrict__ col,
                         const int* __restrict__ rowptr, int* __restrict__ fill,
                         const float* __restrict__ dinv,
                         int* __restrict__ ccol, float* __restrict__ cw) {
    int e = blockIdx.x * blockDim.x + threadIdx.x;
    if (e < E) {
        int r = row[e], c = col[e];
        int p = rowptr[r] + atomicAdd(&fill[r], 1);
        ccol[p] = c;
        cw[p] = dinv[r] * dinv[c];
    }
}

// ---------------- fused SpMM + Chebyshev step ----------------
// s[r,f] = -sum_j cw[j] * vin[ccol[j], f]
// k==1 : tout = s ; heat = c0*base + c1*s
// k>=2 : Tk = 2*s - tkm2 ; tout = Tk ; heat += ck*Tk   (tout may alias tkm2)
__global__ __launch_bounds__(256) void spmm_step(
        const int* __restrict__ rowptr, const int* __restrict__ ccol,
        const float* __restrict__ cw, const float* __restrict__ vin,
        const float* __restrict__ tkm2, const float* __restrict__ base,
        float* __restrict__ tout, float* __restrict__ heat,
        const float* __restrict__ coeffs, int k) {
    int r = blockIdx.x * 4 + (threadIdx.x >> 6);
    int f = threadIdx.x & 63;
    if (r >= N) return;
    int jb = rowptr[r], je = rowptr[r + 1];
    float acc = 0.f;
    for (int j = jb; j < je; ++j) {
        int c = ccol[j];
        float w = cw[j];
        acc = fmaf(w, vin[c * 64 + f], acc);
    }
    float s = -acc;
    int idx = r * 64 + f;
    float ck = coeffs[k];
    if (k == 1) {
        tout[idx] = s;
        heat[idx] = coeffs[0] * base[idx] + ck * s;
    } else {
        float tk = 2.0f * s - tkm2[idx];
        tout[idx] = tk;
        heat[idx] += ck * tk;
    }
}

// ---------------- hidden = relu(x @ Wd + xheat @ Wh1), 64x64 each ----------------
__global__ __launch_bounds__(256) void matmul_hidden(
        const float* __restrict__ x, const float* __restrict__ xh,
        const float* __restrict__ Wd, const float* __restrict__ Wh,
        float* __restrict__ hidden) {
    __shared__ float sWd[64 * 64];
    __shared__ float sWh[64 * 64];
    __shared__ float sx[4][64];
    __shared__ float sxh[4][64];
    int tid = threadIdx.x;
    for (int i = tid; i < 4096; i += 256) { sWd[i] = Wd[i]; sWh[i] = Wh[i]; }
    int rl = tid >> 6, f = tid & 63;
    int row0 = blockIdx.x * 64;
    for (int rr = 0; rr < 64; rr += 4) {
        int r = row0 + rr + rl;
        __syncthreads();
        if (r < N) { sx[rl][f] = x[r * 64 + f]; sxh[rl][f] = xh[r * 64 + f]; }
        __syncthreads();
        if (r < N) {
            float acc = 0.f;
#pragma unroll
            for (int kk = 0; kk < 64; kk++) {
                acc = fmaf(sx[rl][kk], sWd[kk * 64 + f], acc);
                acc = fmaf(sxh[rl][kk], sWh[kk * 64 + f], acc);
            }
            hidden[r * 64 + f] = fmaxf(acc, 0.f);
        }
    }
}

// ---------------- out = log_softmax(h @ W1 + hh @ W2), 64->32 ----------------
__global__ __launch_bounds__(256) void matmul_out(
        const float* __restrict__ h, const float* __restrict__ hh,
        const float* __restrict__ W1, const float* __restrict__ W2,
        float* __restrict__ out) {
    __shared__ float sW1[64 * 32];
    __shared__ float sW2[64 * 32];
    __shared__ float sh[8][64];
    __shared__ float shh[8][64];
    int tid = threadIdx.x;
    for (int i = tid; i < 2048; i += 256) { sW1[i] = W1[i]; sW2[i] = W2[i]; }
    int rl = tid >> 5, c = tid & 31;
    int row0 = blockIdx.x * 64;
    for (int rr = 0; rr < 64; rr += 8) {
        __syncthreads();
        for (int i = tid; i < 512; i += 256) {
            int rl2 = i >> 6, f2 = i & 63;
            int r2 = row0 + rr + rl2;
            float hv = 0.f, hhv = 0.f;
            if (r2 < N) { hv = h[r2 * 64 + f2]; hhv = hh[r2 * 64 + f2]; }
            sh[rl2][f2] = hv; shh[rl2][f2] = hhv;
        }
        __syncthreads();
        int r = row0 + rr + rl;
        if (r < N) {
            float acc = 0.f;
#pragma unroll
            for (int kk = 0; kk < 64; kk++) {
                acc = fmaf(sh[rl][kk], sW1[kk * 32 + c], acc);
                acc = fmaf(shh[rl][kk], sW2[kk * 32 + c], acc);
            }
            float mx = acc;
            for (int o = 16; o > 0; o >>= 1) mx = fmaxf(mx, __shfl_xor(mx, o, 32));
            float ex = expf(acc - mx);
            float sum = ex;
            for (int o = 16; o > 0; o >>= 1) sum += __shfl_xor(sum, o, 32);
            out[r * 32 + c] = acc - mx - logf(sum);
        }
    }
}

extern "C" void kernel_launch(void* const* d_in, const int* in_sizes, int n_in,
                              void* d_out, int out_size, void* d_ws, size_t ws_size,
                              hipStream_t stream) {
    const float* x   = (const float*)d_in[0];
    const int*   ei  = (const int*)d_in[1];
    const float* Wd  = (const float*)d_in[2];
    const float* Wh1 = (const float*)d_in[3];
    const float* Whd = (const float*)d_in[4];
    const float* Wh2 = (const float*)d_in[5];
    const float* tp  = (const float*)d_in[6];
    const int* row = ei;
    const int* col = ei + E;

    // workspace layout (256B aligned slices)
    size_t off = 0;
    auto alloc = [&](size_t bytes) -> void* {
        void* p = (char*)d_ws + off;
        off += (bytes + 255) & ~(size_t)255;
        return p;
    };
    int*   deg    = (int*)alloc((size_t)N * 4);
    int*   rowptr = (int*)alloc((size_t)(N + 1) * 4);
    int*   fillc  = (int*)alloc((size_t)N * 4);
    float* dinv   = (float*)alloc((size_t)N * 4);
    float* coeffs = (float*)alloc(KCHEB * 4);
    int*   ccol   = (int*)alloc((size_t)E * 4);
    float* cw     = (float*)alloc((size_t)E * 4);
    float* Ta     = (float*)alloc((size_t)N * 64 * 4);
    float* Tb     = (float*)alloc((size_t)N * 64 * 4);
    float* heat   = (float*)alloc((size_t)N * 64 * 4);
    float* hidden = (float*)alloc((size_t)N * 64 * 4);

    hipMemsetAsync(deg, 0, (size_t)N * 4, stream);
    hipMemsetAsync(fillc, 0, (size_t)N * 4, stream);

    count_deg<<<(E + 255) / 256, 256, 0, stream>>>(row, deg);
    scan_deg<<<1, 1024, 0, stream>>>(deg, rowptr);
    compute_dinv<<<(N + 255) / 256, 256, 0, stream>>>(rowptr, dinv);
    compute_coeffs<<<1, 64, 0, stream>>>(tp, coeffs);
    fill_csr<<<(E + 255) / 256, 256, 0, stream>>>(row, col, rowptr, fillc, dinv, ccol, cw);

    const int spmm_grid = (N + 3) / 4;

    // ---- heat phase 1: input x ----
    spmm_step<<<spmm_grid, 256, 0, stream>>>(rowptr, ccol, cw, x, x, x, Tb, heat, coeffs, 1);
    {
        const float* tkm2 = x;
        float* tkm1 = Tb;
        for (int k = 2; k < KCHEB; k++) {
            float* tout = (k == 2) ? Ta : (float*)tkm2;
            spmm_step<<<spmm_grid, 256, 0, stream>>>(rowptr, ccol, cw, tkm1, tkm2, x, tout, heat, coeffs, k);
            tkm2 = tkm1; tkm1 = tout;
        }
    }

    matmul_hidden<<<(N + 63) / 64, 256, 0, stream>>>(x, heat, Wd, Wh1, hidden);

    // ---- heat phase 2: input hidden (reuse heat buffer for output) ----
    spmm_step<<<spmm_grid, 256, 0, stream>>>(rowptr, ccol, cw, hidden, hidden, hidden, Tb, heat, coeffs, 1);
    {
        const float* tkm2 = hidden;
        float* tkm1 = Tb;
        for (int k = 2; k < KCHEB; k++) {
            float* tout = (k == 2) ? Ta : (float*)tkm2;
            spmm_step<<<spmm_grid, 256, 0, stream>>>(rowptr, ccol, cw, tkm1, tkm2, hidden, tout, heat, coeffs, k);
            tkm2 = tkm1; tkm1 = tout;
        }
    }

    matmul_out<<<(N + 63) / 64, 256, 0, stream>>>(hidden, heat, Whd, Wh2, (float*)d_out);
}

// Round 2
// 950.065 us; speedup vs baseline: 1.8472x; 1.8472x over previous
//
#include <hip/hip_runtime.h>
#include <math.h>

#define N 50000
#define E 800000
#define HID 64
#define OUTC 32
#define KCHEB 10
#define BT 20

// ---------------- degree count ----------------
__global__ void count_deg(const int* __restrict__ row, int* __restrict__ deg) {
    int e = blockIdx.x * blockDim.x + threadIdx.x;
    if (e < E) atomicAdd(&deg[row[e]], 1);
}

// ---------------- single-block exclusive scan over deg -> rowptr ----------------
__global__ __launch_bounds__(1024) void scan_deg(const int* __restrict__ deg, int* __restrict__ rowptr) {
    __shared__ int part[1024];
    int t = threadIdx.x;
    const int C = (N + 1023) / 1024;  // 49
    int begin = t * C;
    int end = begin + C; if (end > N) end = N;
    int s = 0;
    if (begin < N) for (int i = begin; i < end; i++) s += deg[i];
    part[t] = s;
    __syncthreads();
    for (int ofs = 1; ofs < 1024; ofs <<= 1) {
        int v = (t >= ofs) ? part[t - ofs] : 0;
        __syncthreads();
        part[t] += v;
        __syncthreads();
    }
    int run = (t == 0) ? 0 : part[t - 1];
    if (begin < N) {
        for (int i = begin; i < end; i++) { rowptr[i] = run; run += deg[i]; }
    }
    if (t == 1023) rowptr[N] = part[1023];
}

// ---------------- dinv from rowptr diffs ----------------
__global__ void compute_dinv(const int* __restrict__ rowptr, float* __restrict__ dinv) {
    int r = blockIdx.x * blockDim.x + threadIdx.x;
    if (r < N) {
        int d = rowptr[r + 1] - rowptr[r];
        dinv[r] = (d > 0) ? (1.0f / sqrtf((float)d)) : 0.0f;
    }
}

// ---------------- Chebyshev/Bessel coefficients ----------------
__global__ void compute_coeffs(const float* __restrict__ tptr, float* __restrict__ coeffs) {
    int v = threadIdx.x;
    if (v < KCHEB) {
        float t = tptr[0];
        float lt = logf(0.5f * t);
        float s = 0.f;
        for (int m = 0; m < BT; m++) {
            float lg = lgammaf((float)m + 1.0f) + lgammaf((float)(m + v) + 1.0f);
            s += expf((2.0f * m + (float)v) * lt - lg);
        }
        float c;
        if (v == 0) c = s;
        else c = ((v & 1) == 0) ? 2.0f * s : -2.0f * s;
        coeffs[v] = c;
    }
}

// ---------------- CSR fill (counting sort by row) ----------------
__global__ void fill_csr(const int* __restrict__ row, const int* __restrict__ col,
                         const int* __restrict__ rowptr, int* __restrict__ fill,
                         const float* __restrict__ dinv,
                         int* __restrict__ ccol, float* __restrict__ cw) {
    int e = blockIdx.x * blockDim.x + threadIdx.x;
    if (e < E) {
        int r = row[e], c = col[e];
        int p = rowptr[r] + atomicAdd(&fill[r], 1);
        ccol[p] = c;
        cw[p] = dinv[r] * dinv[c];
    }
}

// ---------------- fused SpMM + Chebyshev step (float4, 4 rows/wave) ----------------
// 16 lanes per row, 4 features per lane. Cooperative index prefetch:
// the 16-lane group loads 16 (ccol,cw) pairs coalesced, then shfl-broadcasts.
// s[r,:] = -sum_j cw[j] * vin[ccol[j],:]
// k==1 : tout = s ; heat = c0*base + c1*s
// k>=2 : Tk = 2*s - tkm2 ; tout = Tk ; heat += ck*Tk
__global__ __launch_bounds__(256) void spmm_step(
        const int* __restrict__ rowptr, const int* __restrict__ ccol,
        const float* __restrict__ cw, const float4* __restrict__ vin,
        const float4* __restrict__ tkm2, const float4* __restrict__ base,
        float4* __restrict__ tout, float4* __restrict__ heat,
        const float* __restrict__ coeffs, int k) {
    int tid = threadIdx.x;
    int lane16 = tid & 15;          // feature quad
    int grpbase = tid & 48;         // wave-relative base lane of this 16-lane group
    int r = blockIdx.x * 16 + (tid >> 4);   // grid = 3125 -> exactly N rows

    int jb = rowptr[r], je = rowptr[r + 1];
    float4 acc; acc.x = 0.f; acc.y = 0.f; acc.z = 0.f; acc.w = 0.f;

    for (int j0 = jb; j0 < je; j0 += 16) {
        int jj = j0 + lane16;
        int myc = 0; float myw = 0.f;
        if (jj < je) { myc = ccol[jj]; myw = cw[jj]; }
        int cnt = je - j0;
        if (cnt >= 16) {
#pragma unroll
            for (int i = 0; i < 16; i++) {
                int c = __shfl(myc, grpbase + i, 64);
                float w = __shfl(myw, grpbase + i, 64);
                float4 v = vin[c * 16 + lane16];
                acc.x = fmaf(w, v.x, acc.x);
                acc.y = fmaf(w, v.y, acc.y);
                acc.z = fmaf(w, v.z, acc.z);
                acc.w = fmaf(w, v.w, acc.w);
            }
        } else {
            for (int i = 0; i < cnt; i++) {
                int c = __shfl(myc, grpbase + i, 64);
                float w = __shfl(myw, grpbase + i, 64);
                float4 v = vin[c * 16 + lane16];
                acc.x = fmaf(w, v.x, acc.x);
                acc.y = fmaf(w, v.y, acc.y);
                acc.z = fmaf(w, v.z, acc.z);
                acc.w = fmaf(w, v.w, acc.w);
            }
        }
    }

    float4 s; s.x = -acc.x; s.y = -acc.y; s.z = -acc.z; s.w = -acc.w;
    int idx = r * 16 + lane16;
    float ck = coeffs[k];
    if (k == 1) {
        float c0 = coeffs[0];
        float4 b = base[idx];
        tout[idx] = s;
        float4 h;
        h.x = fmaf(ck, s.x, c0 * b.x);
        h.y = fmaf(ck, s.y, c0 * b.y);
        h.z = fmaf(ck, s.z, c0 * b.z);
        h.w = fmaf(ck, s.w, c0 * b.w);
        heat[idx] = h;
    } else {
        float4 tm = tkm2[idx];
        float4 tk;
        tk.x = 2.0f * s.x - tm.x;
        tk.y = 2.0f * s.y - tm.y;
        tk.z = 2.0f * s.z - tm.z;
        tk.w = 2.0f * s.w - tm.w;
        tout[idx] = tk;
        float4 h = heat[idx];
        h.x = fmaf(ck, tk.x, h.x);
        h.y = fmaf(ck, tk.y, h.y);
        h.z = fmaf(ck, tk.z, h.z);
        h.w = fmaf(ck, tk.w, h.w);
        heat[idx] = h;
    }
}

// ---------------- hidden = relu(x @ Wd + xheat @ Wh1), 64x64 each ----------------
__global__ __launch_bounds__(256) void matmul_hidden(
        const float* __restrict__ x, const float* __restrict__ xh,
        const float* __restrict__ Wd, const float* __restrict__ Wh,
        float* __restrict__ hidden) {
    __shared__ float sWd[64 * 64];
    __shared__ float sWh[64 * 64];
    __shared__ float sx[4][64];
    __shared__ float sxh[4][64];
    int tid = threadIdx.x;
    for (int i = tid; i < 4096; i += 256) { sWd[i] = Wd[i]; sWh[i] = Wh[i]; }
    int rl = tid >> 6, f = tid & 63;
    int row0 = blockIdx.x * 64;
    for (int rr = 0; rr < 64; rr += 4) {
        int r = row0 + rr + rl;
        __syncthreads();
        if (r < N) { sx[rl][f] = x[r * 64 + f]; sxh[rl][f] = xh[r * 64 + f]; }
        __syncthreads();
        if (r < N) {
            float acc = 0.f;
#pragma unroll
            for (int kk = 0; kk < 64; kk++) {
                acc = fmaf(sx[rl][kk], sWd[kk * 64 + f], acc);
                acc = fmaf(sxh[rl][kk], sWh[kk * 64 + f], acc);
            }
            hidden[r * 64 + f] = fmaxf(acc, 0.f);
        }
    }
}

// ---------------- out = log_softmax(h @ W1 + hh @ W2), 64->32 ----------------
__global__ __launch_bounds__(256) void matmul_out(
        const float* __restrict__ h, const float* __restrict__ hh,
        const float* __restrict__ W1, const float* __restrict__ W2,
        float* __restrict__ out) {
    __shared__ float sW1[64 * 32];
    __shared__ float sW2[64 * 32];
    __shared__ float sh[8][64];
    __shared__ float shh[8][64];
    int tid = threadIdx.x;
    for (int i = tid; i < 2048; i += 256) { sW1[i] = W1[i]; sW2[i] = W2[i]; }
    int rl = tid >> 5, c = tid & 31;
    int row0 = blockIdx.x * 64;
    for (int rr = 0; rr < 64; rr += 8) {
        __syncthreads();
        for (int i = tid; i < 512; i += 256) {
            int rl2 = i >> 6, f2 = i & 63;
            int r2 = row0 + rr + rl2;
            float hv = 0.f, hhv = 0.f;
            if (r2 < N) { hv = h[r2 * 64 + f2]; hhv = hh[r2 * 64 + f2]; }
            sh[rl2][f2] = hv; shh[rl2][f2] = hhv;
        }
        __syncthreads();
        int r = row0 + rr + rl;
        if (r < N) {
            float acc = 0.f;
#pragma unroll
            for (int kk = 0; kk < 64; kk++) {
                acc = fmaf(sh[rl][kk], sW1[kk * 32 + c], acc);
                acc = fmaf(shh[rl][kk], sW2[kk * 32 + c], acc);
            }
            float mx = acc;
            for (int o = 16; o > 0; o >>= 1) mx = fmaxf(mx, __shfl_xor(mx, o, 32));
            float ex = expf(acc - mx);
            float sum = ex;
            for (int o = 16; o > 0; o >>= 1) sum += __shfl_xor(sum, o, 32);
            out[r * 32 + c] = acc - mx - logf(sum);
        }
    }
}

extern "C" void kernel_launch(void* const* d_in, const int* in_sizes, int n_in,
                              void* d_out, int out_size, void* d_ws, size_t ws_size,
                              hipStream_t stream) {
    const float* x   = (const float*)d_in[0];
    const int*   ei  = (const int*)d_in[1];
    const float* Wd  = (const float*)d_in[2];
    const float* Wh1 = (const float*)d_in[3];
    const float* Whd = (const float*)d_in[4];
    const float* Wh2 = (const float*)d_in[5];
    const float* tp  = (const float*)d_in[6];
    const int* row = ei;
    const int* col = ei + E;

    size_t off = 0;
    auto alloc = [&](size_t bytes) -> void* {
        void* p = (char*)d_ws + off;
        off += (bytes + 255) & ~(size_t)255;
        return p;
    };
    int*   deg    = (int*)alloc((size_t)N * 4);
    int*   rowptr = (int*)alloc((size_t)(N + 1) * 4);
    int*   fillc  = (int*)alloc((size_t)N * 4);
    float* dinv   = (float*)alloc((size_t)N * 4);
    float* coeffs = (float*)alloc(KCHEB * 4);
    int*   ccol   = (int*)alloc((size_t)E * 4);
    float* cw     = (float*)alloc((size_t)E * 4);
    float* Ta     = (float*)alloc((size_t)N * 64 * 4);
    float* Tb     = (float*)alloc((size_t)N * 64 * 4);
    float* heat   = (float*)alloc((size_t)N * 64 * 4);
    float* hidden = (float*)alloc((size_t)N * 64 * 4);

    hipMemsetAsync(deg, 0, (size_t)N * 4, stream);
    hipMemsetAsync(fillc, 0, (size_t)N * 4, stream);

    count_deg<<<(E + 255) / 256, 256, 0, stream>>>(row, deg);
    scan_deg<<<1, 1024, 0, stream>>>(deg, rowptr);
    compute_dinv<<<(N + 255) / 256, 256, 0, stream>>>(rowptr, dinv);
    compute_coeffs<<<1, 64, 0, stream>>>(tp, coeffs);
    fill_csr<<<(E + 255) / 256, 256, 0, stream>>>(row, col, rowptr, fillc, dinv, ccol, cw);

    const int spmm_grid = N / 16;  // 3125, exact

    // ---- heat phase 1: input x ----
    spmm_step<<<spmm_grid, 256, 0, stream>>>(rowptr, ccol, cw, (const float4*)x,
                                             (const float4*)x, (const float4*)x,
                                             (float4*)Tb, (float4*)heat, coeffs, 1);
    {
        const float* tkm2 = x;
        float* tkm1 = Tb;
        for (int k = 2; k < KCHEB; k++) {
            float* tout = (k == 2) ? Ta : (float*)tkm2;
            spmm_step<<<spmm_grid, 256, 0, stream>>>(rowptr, ccol, cw, (const float4*)tkm1,
                                                     (const float4*)tkm2, (const float4*)x,
                                                     (float4*)tout, (float4*)heat, coeffs, k);
            tkm2 = tkm1; tkm1 = tout;
        }
    }

    matmul_hidden<<<(N + 63) / 64, 256, 0, stream>>>(x, heat, Wd, Wh1, hidden);

    // ---- heat phase 2: input hidden ----
    spmm_step<<<spmm_grid, 256, 0, stream>>>(rowptr, ccol, cw, (const float4*)hidden,
                                             (const float4*)hidden, (const float4*)hidden,
                                             (float4*)Tb, (float4*)heat, coeffs, 1);
    {
        const float* tkm2 = hidden;
        float* tkm1 = Tb;
        for (int k = 2; k < KCHEB; k++) {
            float* tout = (k == 2) ? Ta : (float*)tkm2;
            spmm_step<<<spmm_grid, 256, 0, stream>>>(rowptr, ccol, cw, (const float4*)tkm1,
                                                     (const float4*)tkm2, (const float4*)hidden,
                                                     (float4*)tout, (float4*)heat, coeffs, k);
            tkm2 = tkm1; tkm1 = tout;
        }
    }

    matmul_out<<<(N + 63) / 64, 256, 0, stream>>>(hidden, heat, Whd, Wh2, (float*)d_out);
}

// Round 3
// 488.088 us; speedup vs baseline: 3.5955x; 1.9465x over previous
//
#include <hip/hip_runtime.h>
#include <math.h>

#define N 50000
#define E 800000
#define HID 64
#define OUTC 32
#define KCHEB 10
#define BT 20
#define SCAN_BLOCKS 196   // ceil(50000/256)

// ---------------- degree count ----------------
__global__ void count_deg(const int* __restrict__ row, int* __restrict__ deg) {
    int e = blockIdx.x * blockDim.x + threadIdx.x;
    if (e < E) atomicAdd(&deg[row[e]], 1);
}

// ---------------- multi-block scan: A) per-block sums ----------------
__global__ __launch_bounds__(256) void scan_a(const int* __restrict__ deg, int* __restrict__ blocksum) {
    __shared__ int sm[256];
    int t = threadIdx.x;
    int i = blockIdx.x * 256 + t;
    sm[t] = (i < N) ? deg[i] : 0;
    __syncthreads();
    for (int ofs = 128; ofs > 0; ofs >>= 1) {
        if (t < ofs) sm[t] += sm[t + ofs];
        __syncthreads();
    }
    if (t == 0) blocksum[blockIdx.x] = sm[0];
}

// ---------------- B) scan of block sums (single small block) ----------------
__global__ __launch_bounds__(256) void scan_b(const int* __restrict__ blocksum,
                                              int* __restrict__ blockoff, int* __restrict__ rowptr) {
    __shared__ int sm[256];
    int t = threadIdx.x;
    int v = (t < SCAN_BLOCKS) ? blocksum[t] : 0;
    sm[t] = v;
    __syncthreads();
    for (int ofs = 1; ofs < 256; ofs <<= 1) {
        int u = (t >= ofs) ? sm[t - ofs] : 0;
        __syncthreads();
        sm[t] += u;
        __syncthreads();
    }
    if (t < SCAN_BLOCKS) blockoff[t] = sm[t] - v;   // exclusive
    if (t == SCAN_BLOCKS - 1) rowptr[N] = sm[t];
}

// ---------------- C) per-block local scan + offset -> rowptr ----------------
__global__ __launch_bounds__(256) void scan_c(const int* __restrict__ deg, const int* __restrict__ blockoff,
                                              int* __restrict__ rowptr) {
    __shared__ int sm[256];
    int t = threadIdx.x;
    int i = blockIdx.x * 256 + t;
    int d = (i < N) ? deg[i] : 0;
    sm[t] = d;
    __syncthreads();
    for (int ofs = 1; ofs < 256; ofs <<= 1) {
        int u = (t >= ofs) ? sm[t - ofs] : 0;
        __syncthreads();
        sm[t] += u;
        __syncthreads();
    }
    if (i < N) rowptr[i] = blockoff[blockIdx.x] + sm[t] - d;  // exclusive
}

// ---------------- dinv from rowptr diffs ----------------
__global__ void compute_dinv(const int* __restrict__ rowptr, float* __restrict__ dinv) {
    int r = blockIdx.x * blockDim.x + threadIdx.x;
    if (r < N) {
        int d = rowptr[r + 1] - rowptr[r];
        dinv[r] = (d > 0) ? (1.0f / sqrtf((float)d)) : 0.0f;
    }
}

// ---------------- Chebyshev/Bessel coefficients + kmax ----------------
__global__ void compute_coeffs(const float* __restrict__ tptr, float* __restrict__ coeffs,
                               int* __restrict__ kmaxp) {
    int v = threadIdx.x;
    __shared__ float sc[KCHEB];
    if (v < KCHEB) {
        float t = tptr[0];
        float lt = logf(0.5f * t);
        float s = 0.f;
        for (int m = 0; m < BT; m++) {
            float lg = lgammaf((float)m + 1.0f) + lgammaf((float)(m + v) + 1.0f);
            s += expf((2.0f * m + (float)v) * lt - lg);
        }
        float c;
        if (v == 0) c = s;
        else c = ((v & 1) == 0) ? 2.0f * s : -2.0f * s;
        coeffs[v] = c;
        sc[v] = c;
    }
    __syncthreads();
    if (v == 0) {
        // kmax = largest k whose coefficient is numerically relevant
        float c0 = fabsf(sc[0]);
        int kmax = 1;
        for (int k = 1; k < KCHEB; k++)
            if (fabsf(sc[k]) >= 1e-6f * c0) kmax = k;
        kmaxp[0] = kmax;
    }
}

// ---------------- CSR fill (counting sort by row) ----------------
__global__ void fill_csr(const int* __restrict__ row, const int* __restrict__ col,
                         const int* __restrict__ rowptr, int* __restrict__ fill,
                         const float* __restrict__ dinv,
                         int* __restrict__ ccol, float* __restrict__ cw) {
    int e = blockIdx.x * blockDim.x + threadIdx.x;
    if (e < E) {
        int r = row[e], c = col[e];
        int p = rowptr[r] + atomicAdd(&fill[r], 1);
        ccol[p] = c;
        cw[p] = dinv[r] * dinv[c];
    }
}

// ---------------- fused SpMM + Chebyshev step (float4, 4 rows/wave) ----------------
// Early-exits (data-driven) when k > kmax: contribution below 1e-6 relative.
__global__ __launch_bounds__(256) void spmm_step(
        const int* __restrict__ rowptr, const int* __restrict__ ccol,
        const float* __restrict__ cw, const float4* __restrict__ vin,
        const float4* __restrict__ tkm2, const float4* __restrict__ base,
        float4* __restrict__ tout, float4* __restrict__ heat,
        const float* __restrict__ coeffs, const int* __restrict__ kmaxp, int k) {
    if (k > 1 && k > kmaxp[0]) return;   // uniform branch, negligible-coefficient step
    int tid = threadIdx.x;
    int lane16 = tid & 15;
    int grpbase = tid & 48;
    int r = blockIdx.x * 16 + (tid >> 4);

    int jb = rowptr[r], je = rowptr[r + 1];
    float4 acc; acc.x = 0.f; acc.y = 0.f; acc.z = 0.f; acc.w = 0.f;

    for (int j0 = jb; j0 < je; j0 += 16) {
        int jj = j0 + lane16;
        int myc = 0; float myw = 0.f;
        if (jj < je) { myc = ccol[jj]; myw = cw[jj]; }
        int cnt = je - j0;
        if (cnt >= 16) {
#pragma unroll
            for (int i = 0; i < 16; i++) {
                int c = __shfl(myc, grpbase + i, 64);
                float w = __shfl(myw, grpbase + i, 64);
                float4 v = vin[c * 16 + lane16];
                acc.x = fmaf(w, v.x, acc.x);
                acc.y = fmaf(w, v.y, acc.y);
                acc.z = fmaf(w, v.z, acc.z);
                acc.w = fmaf(w, v.w, acc.w);
            }
        } else {
            for (int i = 0; i < cnt; i++) {
                int c = __shfl(myc, grpbase + i, 64);
                float w = __shfl(myw, grpbase + i, 64);
                float4 v = vin[c * 16 + lane16];
                acc.x = fmaf(w, v.x, acc.x);
                acc.y = fmaf(w, v.y, acc.y);
                acc.z = fmaf(w, v.z, acc.z);
                acc.w = fmaf(w, v.w, acc.w);
            }
        }
    }

    float4 s; s.x = -acc.x; s.y = -acc.y; s.z = -acc.z; s.w = -acc.w;
    int idx = r * 16 + lane16;
    float ck = coeffs[k];
    if (k == 1) {
        float c0 = coeffs[0];
        float4 b = base[idx];
        tout[idx] = s;
        float4 h;
        h.x = fmaf(ck, s.x, c0 * b.x);
        h.y = fmaf(ck, s.y, c0 * b.y);
        h.z = fmaf(ck, s.z, c0 * b.z);
        h.w = fmaf(ck, s.w, c0 * b.w);
        heat[idx] = h;
    } else {
        float4 tm = tkm2[idx];
        float4 tk;
        tk.x = 2.0f * s.x - tm.x;
        tk.y = 2.0f * s.y - tm.y;
        tk.z = 2.0f * s.z - tm.z;
        tk.w = 2.0f * s.w - tm.w;
        tout[idx] = tk;
        float4 h = heat[idx];
        h.x = fmaf(ck, tk.x, h.x);
        h.y = fmaf(ck, tk.y, h.y);
        h.z = fmaf(ck, tk.z, h.z);
        h.w = fmaf(ck, tk.w, h.w);
        heat[idx] = h;
    }
}

// ---------------- hidden = relu(x @ Wd + xheat @ Wh1), 64x64 each ----------------
__global__ __launch_bounds__(256) void matmul_hidden(
        const float* __restrict__ x, const float* __restrict__ xh,
        const float* __restrict__ Wd, const float* __restrict__ Wh,
        float* __restrict__ hidden) {
    __shared__ float sWd[64 * 64];
    __shared__ float sWh[64 * 64];
    __shared__ float sx[4][64];
    __shared__ float sxh[4][64];
    int tid = threadIdx.x;
    for (int i = tid; i < 4096; i += 256) { sWd[i] = Wd[i]; sWh[i] = Wh[i]; }
    int rl = tid >> 6, f = tid & 63;
    int row0 = blockIdx.x * 64;
    for (int rr = 0; rr < 64; rr += 4) {
        int r = row0 + rr + rl;
        __syncthreads();
        if (r < N) { sx[rl][f] = x[r * 64 + f]; sxh[rl][f] = xh[r * 64 + f]; }
        __syncthreads();
        if (r < N) {
            float acc = 0.f;
#pragma unroll
            for (int kk = 0; kk < 64; kk++) {
                acc = fmaf(sx[rl][kk], sWd[kk * 64 + f], acc);
                acc = fmaf(sxh[rl][kk], sWh[kk * 64 + f], acc);
            }
            hidden[r * 64 + f] = fmaxf(acc, 0.f);
        }
    }
}

// ---------------- out = log_softmax(h @ W1 + hh @ W2), 64->32 ----------------
__global__ __launch_bounds__(256) void matmul_out(
        const float* __restrict__ h, const float* __restrict__ hh,
        const float* __restrict__ W1, const float* __restrict__ W2,
        float* __restrict__ out) {
    __shared__ float sW1[64 * 32];
    __shared__ float sW2[64 * 32];
    __shared__ float sh[8][64];
    __shared__ float shh[8][64];
    int tid = threadIdx.x;
    for (int i = tid; i < 2048; i += 256) { sW1[i] = W1[i]; sW2[i] = W2[i]; }
    int rl = tid >> 5, c = tid & 31;
    int row0 = blockIdx.x * 64;
    for (int rr = 0; rr < 64; rr += 8) {
        __syncthreads();
        for (int i = tid; i < 512; i += 256) {
            int rl2 = i >> 6, f2 = i & 63;
            int r2 = row0 + rr + rl2;
            float hv = 0.f, hhv = 0.f;
            if (r2 < N) { hv = h[r2 * 64 + f2]; hhv = hh[r2 * 64 + f2]; }
            sh[rl2][f2] = hv; shh[rl2][f2] = hhv;
        }
        __syncthreads();
        int r = row0 + rr + rl;
        if (r < N) {
            float acc = 0.f;
#pragma unroll
            for (int kk = 0; kk < 64; kk++) {
                acc = fmaf(sh[rl][kk], sW1[kk * 32 + c], acc);
                acc = fmaf(shh[rl][kk], sW2[kk * 32 + c], acc);
            }
            float mx = acc;
            for (int o = 16; o > 0; o >>= 1) mx = fmaxf(mx, __shfl_xor(mx, o, 32));
            float ex = expf(acc - mx);
            float sum = ex;
            for (int o = 16; o > 0; o >>= 1) sum += __shfl_xor(sum, o, 32);
            out[r * 32 + c] = acc - mx - logf(sum);
        }
    }
}

extern "C" void kernel_launch(void* const* d_in, const int* in_sizes, int n_in,
                              void* d_out, int out_size, void* d_ws, size_t ws_size,
                              hipStream_t stream) {
    const float* x   = (const float*)d_in[0];
    const int*   ei  = (const int*)d_in[1];
    const float* Wd  = (const float*)d_in[2];
    const float* Wh1 = (const float*)d_in[3];
    const float* Whd = (const float*)d_in[4];
    const float* Wh2 = (const float*)d_in[5];
    const float* tp  = (const float*)d_in[6];
    const int* row = ei;
    const int* col = ei + E;

    size_t off = 0;
    auto alloc = [&](size_t bytes) -> void* {
        void* p = (char*)d_ws + off;
        off += (bytes + 255) & ~(size_t)255;
        return p;
    };
    int*   deg      = (int*)alloc((size_t)N * 4);
    int*   rowptr   = (int*)alloc((size_t)(N + 1) * 4);
    int*   fillc    = (int*)alloc((size_t)N * 4);
    float* dinv     = (float*)alloc((size_t)N * 4);
    float* coeffs   = (float*)alloc(KCHEB * 4);
    int*   kmaxp    = (int*)alloc(4);
    int*   blocksum = (int*)alloc(SCAN_BLOCKS * 4);
    int*   blockoff = (int*)alloc(SCAN_BLOCKS * 4);
    int*   ccol     = (int*)alloc((size_t)E * 4);
    float* cw       = (float*)alloc((size_t)E * 4);
    float* Ta       = (float*)alloc((size_t)N * 64 * 4);
    float* Tb       = (float*)alloc((size_t)N * 64 * 4);
    float* heat     = (float*)alloc((size_t)N * 64 * 4);
    float* hidden   = (float*)alloc((size_t)N * 64 * 4);

    hipMemsetAsync(deg, 0, (size_t)N * 4, stream);
    hipMemsetAsync(fillc, 0, (size_t)N * 4, stream);

    count_deg<<<(E + 255) / 256, 256, 0, stream>>>(row, deg);
    scan_a<<<SCAN_BLOCKS, 256, 0, stream>>>(deg, blocksum);
    scan_b<<<1, 256, 0, stream>>>(blocksum, blockoff, rowptr);
    scan_c<<<SCAN_BLOCKS, 256, 0, stream>>>(deg, blockoff, rowptr);
    compute_dinv<<<(N + 255) / 256, 256, 0, stream>>>(rowptr, dinv);
    compute_coeffs<<<1, 64, 0, stream>>>(tp, coeffs, kmaxp);
    fill_csr<<<(E + 255) / 256, 256, 0, stream>>>(row, col, rowptr, fillc, dinv, ccol, cw);

    const int spmm_grid = N / 16;  // 3125, exact

    // ---- heat phase 1: input x ----
    spmm_step<<<spmm_grid, 256, 0, stream>>>(rowptr, ccol, cw, (const float4*)x,
                                             (const float4*)x, (const float4*)x,
                                             (float4*)Tb, (float4*)heat, coeffs, kmaxp, 1);
    {
        const float* tkm2 = x;
        float* tkm1 = Tb;
        for (int k = 2; k < KCHEB; k++) {
            float* tout = (k == 2) ? Ta : (float*)tkm2;
            spmm_step<<<spmm_grid, 256, 0, stream>>>(rowptr, ccol, cw, (const float4*)tkm1,
                                                     (const float4*)tkm2, (const float4*)x,
                                                     (float4*)tout, (float4*)heat, coeffs, kmaxp, k);
            tkm2 = tkm1; tkm1 = tout;
        }
    }

    matmul_hidden<<<(N + 63) / 64, 256, 0, stream>>>(x, heat, Wd, Wh1, hidden);

    // ---- heat phase 2: input hidden ----
    spmm_step<<<spmm_grid, 256, 0, stream>>>(rowptr, ccol, cw, (const float4*)hidden,
                                             (const float4*)hidden, (const float4*)hidden,
                                             (float4*)Tb, (float4*)heat, coeffs, kmaxp, 1);
    {
        const float* tkm2 = hidden;
        float* tkm1 = Tb;
        for (int k = 2; k < KCHEB; k++) {
            float* tout = (k == 2) ? Ta : (float*)tkm2;
            spmm_step<<<spmm_grid, 256, 0, stream>>>(rowptr, ccol, cw, (const float4*)tkm1,
                                                     (const float4*)tkm2, (const float4*)hidden,
                                                     (float4*)tout, (float4*)heat, coeffs, kmaxp, k);
            tkm2 = tkm1; tkm1 = tout;
        }
    }

    matmul_out<<<(N + 63) / 64, 256, 0, stream>>>(hidden, heat, Whd, Wh2, (float*)d_out);
}

// Round 4
// 403.894 us; speedup vs baseline: 4.3450x; 1.2085x over previous
//
#include <hip/hip_runtime.h>
#include <math.h>

#define N 50000
#define E 800000
#define KCHEB 10
#define BT 20
#define SCAN_BLOCKS 196   // ceil(50000/256)
#define NF 64             // features
#define N64 ((size_t)N * 64)

// ---- bf16 helpers (manual, RNE) ----
__device__ __forceinline__ unsigned f2bf(float x) {
    unsigned u = __float_as_uint(x);
    return (u + 0x7FFFu + ((u >> 16) & 1u)) >> 16;
}
__device__ __forceinline__ float bf2f(unsigned h) {
    return __uint_as_float(h << 16);
}
__device__ __forceinline__ unsigned packbf(float lo, float hi) {
    return f2bf(lo) | (f2bf(hi) << 16);
}

// ---------------- degree count ----------------
__global__ void count_deg(const int* __restrict__ row, int* __restrict__ deg) {
    int e = blockIdx.x * blockDim.x + threadIdx.x;
    if (e < E) atomicAdd(&deg[row[e]], 1);
}

// ---------------- multi-block scan ----------------
__global__ __launch_bounds__(256) void scan_a(const int* __restrict__ deg, int* __restrict__ blocksum) {
    __shared__ int sm[256];
    int t = threadIdx.x;
    int i = blockIdx.x * 256 + t;
    sm[t] = (i < N) ? deg[i] : 0;
    __syncthreads();
    for (int ofs = 128; ofs > 0; ofs >>= 1) {
        if (t < ofs) sm[t] += sm[t + ofs];
        __syncthreads();
    }
    if (t == 0) blocksum[blockIdx.x] = sm[0];
}
__global__ __launch_bounds__(256) void scan_b(const int* __restrict__ blocksum,
                                              int* __restrict__ blockoff, int* __restrict__ rowptr) {
    __shared__ int sm[256];
    int t = threadIdx.x;
    int v = (t < SCAN_BLOCKS) ? blocksum[t] : 0;
    sm[t] = v;
    __syncthreads();
    for (int ofs = 1; ofs < 256; ofs <<= 1) {
        int u = (t >= ofs) ? sm[t - ofs] : 0;
        __syncthreads();
        sm[t] += u;
        __syncthreads();
    }
    if (t < SCAN_BLOCKS) blockoff[t] = sm[t] - v;
    if (t == SCAN_BLOCKS - 1) rowptr[N] = sm[t];
}
__global__ __launch_bounds__(256) void scan_c(const int* __restrict__ deg, const int* __restrict__ blockoff,
                                              int* __restrict__ rowptr) {
    __shared__ int sm[256];
    int t = threadIdx.x;
    int i = blockIdx.x * 256 + t;
    int d = (i < N) ? deg[i] : 0;
    sm[t] = d;
    __syncthreads();
    for (int ofs = 1; ofs < 256; ofs <<= 1) {
        int u = (t >= ofs) ? sm[t - ofs] : 0;
        __syncthreads();
        sm[t] += u;
        __syncthreads();
    }
    if (i < N) rowptr[i] = blockoff[blockIdx.x] + sm[t] - d;
}

// ---------------- dinv ----------------
__global__ void compute_dinv(const int* __restrict__ rowptr, float* __restrict__ dinv) {
    int r = blockIdx.x * blockDim.x + threadIdx.x;
    if (r < N) {
        int d = rowptr[r + 1] - rowptr[r];
        dinv[r] = (d > 0) ? (1.0f / sqrtf((float)d)) : 0.0f;
    }
}

// ---------------- Bessel coefficients + data-driven kmax ----------------
__global__ void compute_coeffs(const float* __restrict__ tptr, float* __restrict__ coeffs,
                               int* __restrict__ kmaxp) {
    int v = threadIdx.x;
    __shared__ float sc[KCHEB];
    if (v < KCHEB) {
        float t = tptr[0];
        float lt = logf(0.5f * t);
        float s = 0.f;
        for (int m = 0; m < BT; m++) {
            float lg = lgammaf((float)m + 1.0f) + lgammaf((float)(m + v) + 1.0f);
            s += expf((2.0f * m + (float)v) * lt - lg);
        }
        float c;
        if (v == 0) c = s;
        else c = ((v & 1) == 0) ? 2.0f * s : -2.0f * s;
        coeffs[v] = c;
        sc[v] = c;
    }
    __syncthreads();
    if (v == 0) {
        float c0 = fabsf(sc[0]);
        int kmax = 1;
        for (int k = 1; k < KCHEB; k++)
            if (fabsf(sc[k]) >= 1e-6f * c0) kmax = k;
        kmaxp[0] = kmax;
    }
}

// ---------------- CSR fill: packed (col, weight) pairs ----------------
__global__ void fill_csr(const int* __restrict__ row, const int* __restrict__ col,
                         const int* __restrict__ rowptr, int* __restrict__ fill,
                         const float* __restrict__ dinv, int2* __restrict__ edges) {
    int e = blockIdx.x * blockDim.x + threadIdx.x;
    if (e < E) {
        int r = row[e], c = col[e];
        int p = rowptr[r] + atomicAdd(&fill[r], 1);
        edges[p] = make_int2(c, __float_as_int(dinv[r] * dinv[c]));
    }
}

// ---------------- f32 -> bf16 convert (8 elems/thread) ----------------
__global__ __launch_bounds__(256) void convert_bf16(const float4* __restrict__ xin,
                                                    uint4* __restrict__ xbf) {
    int i = blockIdx.x * 256 + threadIdx.x;
    if (i >= (int)(N64 / 8)) return;
    float4 a = xin[2 * i], b = xin[2 * i + 1];
    uint4 o;
    o.x = packbf(a.x, a.y); o.y = packbf(a.z, a.w);
    o.z = packbf(b.x, b.y); o.w = packbf(b.z, b.w);
    xbf[i] = o;
}

// ---------------- SpMM Chebyshev step, bf16 everywhere ----------------
// 8 lanes per row, 8 bf16 features (16B) per lane. Predicated full unroll of 8
// (pad gathers hit row 0 -> L1) so all gathers issue independently.
// k==1 : tout = s = -A vin
// k>=2 : tout = 2*s - tkm2
__global__ __launch_bounds__(256) void spmm_step(
        const int* __restrict__ rowptr, const int2* __restrict__ edges,
        const uint4* __restrict__ vin, const uint4* __restrict__ tkm2,
        uint4* __restrict__ tout, const int* __restrict__ kmaxp, int k) {
    if (k > 1 && k > kmaxp[0]) return;
    int tid = threadIdx.x;
    int lane8 = tid & 7;
    int gbase = tid & 56;              // wave-lane base of the 8-lane group
    int r = blockIdx.x * 32 + (tid >> 3);
    if (r >= N) return;
    int jb = rowptr[r], je = rowptr[r + 1];
    float a0=0,a1=0,a2=0,a3=0,a4=0,a5=0,a6=0,a7=0;
    for (int j0 = jb; j0 < je; j0 += 8) {
        int jj = j0 + lane8;
        int myc = 0; float myw = 0.f;
        if (jj < je) { int2 e = edges[jj]; myc = e.x; myw = __int_as_float(e.y); }
#pragma unroll
        for (int i = 0; i < 8; i++) {
            int c = __shfl(myc, gbase + i, 64);
            float w = __shfl(myw, gbase + i, 64);
            uint4 v = vin[c * 8 + lane8];
            a0 = fmaf(w, bf2f(v.x & 0xFFFFu), a0);
            a1 = fmaf(w, bf2f(v.x >> 16),     a1);
            a2 = fmaf(w, bf2f(v.y & 0xFFFFu), a2);
            a3 = fmaf(w, bf2f(v.y >> 16),     a3);
            a4 = fmaf(w, bf2f(v.z & 0xFFFFu), a4);
            a5 = fmaf(w, bf2f(v.z >> 16),     a5);
            a6 = fmaf(w, bf2f(v.w & 0xFFFFu), a6);
            a7 = fmaf(w, bf2f(v.w >> 16),     a7);
        }
    }
    float s0=-a0,s1=-a1,s2=-a2,s3=-a3,s4=-a4,s5=-a5,s6=-a6,s7=-a7;
    int idx = r * 8 + lane8;
    if (k >= 2) {
        uint4 tm = tkm2[idx];
        s0 = 2.f*s0 - bf2f(tm.x & 0xFFFFu);
        s1 = 2.f*s1 - bf2f(tm.x >> 16);
        s2 = 2.f*s2 - bf2f(tm.y & 0xFFFFu);
        s3 = 2.f*s3 - bf2f(tm.y >> 16);
        s4 = 2.f*s4 - bf2f(tm.z & 0xFFFFu);
        s5 = 2.f*s5 - bf2f(tm.z >> 16);
        s6 = 2.f*s6 - bf2f(tm.w & 0xFFFFu);
        s7 = 2.f*s7 - bf2f(tm.w >> 16);
    }
    uint4 o;
    o.x = packbf(s0, s1); o.y = packbf(s2, s3);
    o.z = packbf(s4, s5); o.w = packbf(s6, s7);
    tout[idx] = o;
}

// ---------------- hidden(bf16) = relu(x @ Wd + (Σ ck Tk) @ Wh) ----------------
// Weights in VGPRs (column per lane); x rows + fused heat rows staged in LDS,
// read back as wave-uniform float4 broadcasts. Heat materialization fused here.
__global__ __launch_bounds__(256, 2) void matmul_hidden(
        const float* __restrict__ x, const unsigned short* __restrict__ Tall, int nslots,
        const float* __restrict__ coeffs, const int* __restrict__ kmaxp,
        const float* __restrict__ Wd, const float* __restrict__ Wh,
        unsigned short* __restrict__ hidbf) {
    __shared__ float sx[64][64];
    __shared__ float sh[64][64];
    int tid = threadIdx.x;
    int f = tid & 63, w = tid >> 6;
    float wd[64], wh[64];
#pragma unroll
    for (int k = 0; k < 64; k++) { wd[k] = Wd[k * 64 + f]; wh[k] = Wh[k * 64 + f]; }
    int row0 = blockIdx.x * 64;
    int kmax = kmaxp[0]; if (kmax > KCHEB - 1) kmax = KCHEB - 1;
    float c0 = coeffs[0];
    for (int i = tid; i < 4096; i += 256) {
        int rr = i >> 6, ff = i & 63;
        int r = row0 + rr;
        float xv = 0.f, hv = 0.f;
        if (r < N) {
            xv = x[(size_t)r * 64 + ff];
            hv = c0 * xv;
            for (int j = 1; j <= kmax; j++) {
                int slot = (j - 1) % nslots;
                hv = fmaf(coeffs[j], bf2f(Tall[(size_t)slot * N64 + (size_t)r * 64 + ff]), hv);
            }
        }
        sx[rr][ff] = xv; sh[rr][ff] = hv;
    }
    __syncthreads();
    for (int rr = w * 16; rr < w * 16 + 16; rr++) {
        float acc = 0.f;
#pragma unroll
        for (int k4 = 0; k4 < 64; k4 += 4) {
            float4 xv = *(const float4*)&sx[rr][k4];
            float4 hv = *(const float4*)&sh[rr][k4];
            acc = fmaf(xv.x, wd[k4+0], acc); acc = fmaf(xv.y, wd[k4+1], acc);
            acc = fmaf(xv.z, wd[k4+2], acc); acc = fmaf(xv.w, wd[k4+3], acc);
            acc = fmaf(hv.x, wh[k4+0], acc); acc = fmaf(hv.y, wh[k4+1], acc);
            acc = fmaf(hv.z, wh[k4+2], acc); acc = fmaf(hv.w, wh[k4+3], acc);
        }
        int r = row0 + rr;
        if (r < N) hidbf[(size_t)r * 64 + f] = (unsigned short)f2bf(fmaxf(acc, 0.f));
    }
}

// ---------------- out = log_softmax(hid @ W1 + (Σ ck Uk) @ W2) ----------------
__global__ __launch_bounds__(256, 2) void matmul_out(
        const unsigned short* __restrict__ hidbf, const unsigned short* __restrict__ Tall, int nslots,
        const float* __restrict__ coeffs, const int* __restrict__ kmaxp,
        const float* __restrict__ W1, const float* __restrict__ W2,
        float* __restrict__ out) {
    __shared__ float sa[64][64];
    __shared__ float sb[64][64];
    int tid = threadIdx.x;
    int lane = tid & 63, w = tid >> 6;
    int c = lane & 31, half = lane >> 5;
    float w1[64], w2[64];
#pragma unroll
    for (int k = 0; k < 64; k++) { w1[k] = W1[k * 32 + c]; w2[k] = W2[k * 32 + c]; }
    int row0 = blockIdx.x * 64;
    int kmax = kmaxp[0]; if (kmax > KCHEB - 1) kmax = KCHEB - 1;
    float c0 = coeffs[0];
    for (int i = tid; i < 4096; i += 256) {
        int rr = i >> 6, ff = i & 63;
        int r = row0 + rr;
        float hv = 0.f, h2 = 0.f;
        if (r < N) {
            hv = bf2f(hidbf[(size_t)r * 64 + ff]);
            h2 = c0 * hv;
            for (int j = 1; j <= kmax; j++) {
                int slot = (j - 1) % nslots;
                h2 = fmaf(coeffs[j], bf2f(Tall[(size_t)slot * N64 + (size_t)r * 64 + ff]), h2);
            }
        }
        sa[rr][ff] = hv; sb[rr][ff] = h2;
    }
    __syncthreads();
    for (int rp = 0; rp < 16; rp += 2) {
        int rr = w * 16 + rp + half;
        float acc = 0.f;
#pragma unroll
        for (int k4 = 0; k4 < 64; k4 += 4) {
            float4 av = *(const float4*)&sa[rr][k4];
            float4 bv = *(const float4*)&sb[rr][k4];
            acc = fmaf(av.x, w1[k4+0], acc); acc = fmaf(av.y, w1[k4+1], acc);
            acc = fmaf(av.z, w1[k4+2], acc); acc = fmaf(av.w, w1[k4+3], acc);
            acc = fmaf(bv.x, w2[k4+0], acc); acc = fmaf(bv.y, w2[k4+1], acc);
            acc = fmaf(bv.z, w2[k4+2], acc); acc = fmaf(bv.w, w2[k4+3], acc);
        }
        float mx = acc;
        for (int o = 16; o > 0; o >>= 1) mx = fmaxf(mx, __shfl_xor(mx, o, 32));
        float ex = expf(acc - mx);
        float sum = ex;
        for (int o = 16; o > 0; o >>= 1) sum += __shfl_xor(sum, o, 32);
        int r = row0 + rr;
        if (r < N) out[(size_t)r * 32 + c] = acc - mx - logf(sum);
    }
}

extern "C" void kernel_launch(void* const* d_in, const int* in_sizes, int n_in,
                              void* d_out, int out_size, void* d_ws, size_t ws_size,
                              hipStream_t stream) {
    const float* x   = (const float*)d_in[0];
    const int*   ei  = (const int*)d_in[1];
    const float* Wd  = (const float*)d_in[2];
    const float* Wh1 = (const float*)d_in[3];
    const float* Whd = (const float*)d_in[4];
    const float* Wh2 = (const float*)d_in[5];
    const float* tp  = (const float*)d_in[6];
    const int* row = ei;
    const int* col = ei + E;

    size_t off = 0;
    auto alloc = [&](size_t bytes) -> void* {
        void* p = (char*)d_ws + off;
        off += (bytes + 255) & ~(size_t)255;
        return p;
    };
    int*   deg      = (int*)alloc((size_t)N * 4);
    int*   rowptr   = (int*)alloc((size_t)(N + 1) * 4);
    int*   fillc    = (int*)alloc((size_t)N * 4);
    float* dinv     = (float*)alloc((size_t)N * 4);
    float* coeffs   = (float*)alloc(KCHEB * 4);
    int*   kmaxp    = (int*)alloc(4);
    int*   blocksum = (int*)alloc(SCAN_BLOCKS * 4);
    int*   blockoff = (int*)alloc(SCAN_BLOCKS * 4);
    int2*  edges    = (int2*)alloc((size_t)E * 8);
    unsigned short* xbf    = (unsigned short*)alloc(N64 * 2);
    unsigned short* hidbf  = (unsigned short*)alloc(N64 * 2);
    // T-term slots (bf16, N*64 each) — as many as workspace allows, up to 9
    size_t tbytes = ((N64 * 2 + 255) & ~(size_t)255);
    int nslots = (int)((ws_size - off) / tbytes);
    if (nslots > KCHEB - 1) nslots = KCHEB - 1;
    if (nslots < 1) nslots = 1;
    unsigned short* Tall = (unsigned short*)alloc((size_t)nslots * tbytes);
    auto Tslot = [&](int k) -> unsigned short* {   // buffer for T_k, k>=1
        return (unsigned short*)((char*)Tall + (size_t)((k - 1) % nslots) * tbytes);
    };

    hipMemsetAsync(deg, 0, (size_t)N * 4, stream);
    hipMemsetAsync(fillc, 0, (size_t)N * 4, stream);

    count_deg<<<(E + 255) / 256, 256, 0, stream>>>(row, deg);
    scan_a<<<SCAN_BLOCKS, 256, 0, stream>>>(deg, blocksum);
    scan_b<<<1, 256, 0, stream>>>(blocksum, blockoff, rowptr);
    scan_c<<<SCAN_BLOCKS, 256, 0, stream>>>(deg, blockoff, rowptr);
    compute_dinv<<<(N + 255) / 256, 256, 0, stream>>>(rowptr, dinv);
    compute_coeffs<<<1, 64, 0, stream>>>(tp, coeffs, kmaxp);
    fill_csr<<<(E + 255) / 256, 256, 0, stream>>>(row, col, rowptr, fillc, dinv, edges);
    convert_bf16<<<(int)(N64 / 8 + 255) / 256, 256, 0, stream>>>((const float4*)x, (uint4*)xbf);

    const int spmm_grid = (N + 31) / 32;   // 8 lanes/row, 32 rows/block
    const int mm_grid = (N + 63) / 64;

    // ---- heat phase 1: base = x (bf16 in xbf) ----
    for (int k = 1; k < KCHEB; k++) {
        const uint4* vin = (k == 1) ? (const uint4*)xbf : (const uint4*)Tslot(k - 1);
        const uint4* tm2 = (k == 2) ? (const uint4*)xbf
                         : (k == 1) ? (const uint4*)xbf   // unused at k==1
                         : (const uint4*)Tslot(k - 2);
        spmm_step<<<spmm_grid, 256, 0, stream>>>(rowptr, edges, vin, tm2,
                                                 (uint4*)Tslot(k), kmaxp, k);
    }
    matmul_hidden<<<mm_grid, 256, 0, stream>>>(x, Tall, nslots, coeffs, kmaxp, Wd, Wh1, hidbf);

    // ---- heat phase 2: base = hidden (bf16) ----
    for (int k = 1; k < KCHEB; k++) {
        const uint4* vin = (k == 1) ? (const uint4*)hidbf : (const uint4*)Tslot(k - 1);
        const uint4* tm2 = (k == 2) ? (const uint4*)hidbf
                         : (k == 1) ? (const uint4*)hidbf
                         : (const uint4*)Tslot(k - 2);
        spmm_step<<<spmm_grid, 256, 0, stream>>>(rowptr, edges, vin, tm2,
                                                 (uint4*)Tslot(k), kmaxp, k);
    }
    matmul_out<<<mm_grid, 256, 0, stream>>>(hidbf, Tall, nslots, coeffs, kmaxp, Whd, Wh2, (float*)d_out);
}

// Round 5
// 312.230 us; speedup vs baseline: 5.6206x; 1.2936x over previous
//
#include <hip/hip_runtime.h>
#include <math.h>

#define N 50000
#define E 800000
#define KCHEB 10
#define BT 20
#define SCAN_BLOCKS 196   // ceil(50000/256)
#define N64 ((size_t)N * 64)

typedef __attribute__((ext_vector_type(8))) short short8;   // 8 bf16 = 4 VGPRs
typedef __attribute__((ext_vector_type(4))) float f32x4;    // MFMA acc

// ---- bf16 helpers (manual, RNE) ----
__device__ __forceinline__ unsigned f2bf(float x) {
    unsigned u = __float_as_uint(x);
    return (u + 0x7FFFu + ((u >> 16) & 1u)) >> 16;
}
__device__ __forceinline__ float bf2f(unsigned h) {
    return __uint_as_float(h << 16);
}
__device__ __forceinline__ unsigned packbf(float lo, float hi) {
    return f2bf(lo) | (f2bf(hi) << 16);
}
__device__ __forceinline__ void unpack8(uint4 v, float* f) {
    f[0]=bf2f(v.x&0xFFFFu); f[1]=bf2f(v.x>>16);
    f[2]=bf2f(v.y&0xFFFFu); f[3]=bf2f(v.y>>16);
    f[4]=bf2f(v.z&0xFFFFu); f[5]=bf2f(v.z>>16);
    f[6]=bf2f(v.w&0xFFFFu); f[7]=bf2f(v.w>>16);
}
__device__ __forceinline__ uint4 pack8(const float* f) {
    return make_uint4(packbf(f[0],f[1]),packbf(f[2],f[3]),packbf(f[4],f[5]),packbf(f[6],f[7]));
}

// ---------------- degree count ----------------
__global__ void count_deg(const int* __restrict__ row, int* __restrict__ deg) {
    int e = blockIdx.x * blockDim.x + threadIdx.x;
    if (e < E) atomicAdd(&deg[row[e]], 1);
}

// ---------------- multi-block scan ----------------
__global__ __launch_bounds__(256) void scan_a(const int* __restrict__ deg, int* __restrict__ blocksum) {
    __shared__ int sm[256];
    int t = threadIdx.x;
    int i = blockIdx.x * 256 + t;
    sm[t] = (i < N) ? deg[i] : 0;
    __syncthreads();
    for (int ofs = 128; ofs > 0; ofs >>= 1) {
        if (t < ofs) sm[t] += sm[t + ofs];
        __syncthreads();
    }
    if (t == 0) blocksum[blockIdx.x] = sm[0];
}
__global__ __launch_bounds__(256) void scan_b(const int* __restrict__ blocksum,
                                              int* __restrict__ blockoff, int* __restrict__ rowptr) {
    __shared__ int sm[256];
    int t = threadIdx.x;
    int v = (t < SCAN_BLOCKS) ? blocksum[t] : 0;
    sm[t] = v;
    __syncthreads();
    for (int ofs = 1; ofs < 256; ofs <<= 1) {
        int u = (t >= ofs) ? sm[t - ofs] : 0;
        __syncthreads();
        sm[t] += u;
        __syncthreads();
    }
    if (t < SCAN_BLOCKS) blockoff[t] = sm[t] - v;
    if (t == SCAN_BLOCKS - 1) rowptr[N] = sm[t];
}
__global__ __launch_bounds__(256) void scan_c(const int* __restrict__ deg, const int* __restrict__ blockoff,
                                              int* __restrict__ rowptr) {
    __shared__ int sm[256];
    int t = threadIdx.x;
    int i = blockIdx.x * 256 + t;
    int d = (i < N) ? deg[i] : 0;
    sm[t] = d;
    __syncthreads();
    for (int ofs = 1; ofs < 256; ofs <<= 1) {
        int u = (t >= ofs) ? sm[t - ofs] : 0;
        __syncthreads();
        sm[t] += u;
        __syncthreads();
    }
    if (i < N) rowptr[i] = blockoff[blockIdx.x] + sm[t] - d;
}

// ---------------- dinv ----------------
__global__ void compute_dinv(const int* __restrict__ rowptr, float* __restrict__ dinv) {
    int r = blockIdx.x * blockDim.x + threadIdx.x;
    if (r < N) {
        int d = rowptr[r + 1] - rowptr[r];
        dinv[r] = (d > 0) ? (1.0f / sqrtf((float)d)) : 0.0f;
    }
}

// ---------------- Bessel coefficients + data-driven kmax ----------------
__global__ void compute_coeffs(const float* __restrict__ tptr, float* __restrict__ coeffs,
                               int* __restrict__ kmaxp) {
    int v = threadIdx.x;
    __shared__ float sc[KCHEB];
    if (v < KCHEB) {
        float t = tptr[0];
        float lt = logf(0.5f * t);
        float s = 0.f;
        for (int m = 0; m < BT; m++) {
            float lg = lgammaf((float)m + 1.0f) + lgammaf((float)(m + v) + 1.0f);
            s += expf((2.0f * m + (float)v) * lt - lg);
        }
        float c;
        if (v == 0) c = s;
        else c = ((v & 1) == 0) ? 2.0f * s : -2.0f * s;
        coeffs[v] = c;
        sc[v] = c;
    }
    __syncthreads();
    if (v == 0) {
        float c0 = fabsf(sc[0]);
        int kmax = 1;
        for (int k = 1; k < KCHEB; k++)
            if (fabsf(sc[k]) >= 1e-6f * c0) kmax = k;
        kmaxp[0] = kmax;
    }
}

// ---------------- CSR fill: packed (col, weight) pairs ----------------
__global__ void fill_csr(const int* __restrict__ row, const int* __restrict__ col,
                         const int* __restrict__ rowptr, int* __restrict__ fill,
                         const float* __restrict__ dinv, int2* __restrict__ edges) {
    int e = blockIdx.x * blockDim.x + threadIdx.x;
    if (e < E) {
        int r = row[e], c = col[e];
        int p = rowptr[r] + atomicAdd(&fill[r], 1);
        edges[p] = make_int2(c, __float_as_int(dinv[r] * dinv[c]));
    }
}

// ---------------- f32 -> bf16 convert (8 elems/thread) ----------------
__global__ __launch_bounds__(256) void convert_bf16(const float4* __restrict__ xin,
                                                    uint4* __restrict__ xbf) {
    int i = blockIdx.x * 256 + threadIdx.x;
    if (i >= (int)(N64 / 8)) return;
    float4 a = xin[2 * i], b = xin[2 * i + 1];
    uint4 o;
    o.x = packbf(a.x, a.y); o.y = packbf(a.z, a.w);
    o.z = packbf(b.x, b.y); o.w = packbf(b.z, b.w);
    xbf[i] = o;
}

// ---------------- pack B = [Wtop;Wbot] (128 x ncols, f32) into MFMA B-frags ----
// frag id = kt*(ntiles*64) + nt*64 + lane ; lane holds B[k=kt*32+(lane>>4)*8+j][n=nt*16+(lane&15)]
__global__ void pack_wfrag(const float* __restrict__ Wtop, const float* __restrict__ Wbot,
                           int ncols, uint4* __restrict__ out) {
    int id = blockIdx.x * blockDim.x + threadIdx.x;
    int ntiles = ncols >> 4;
    int total = 4 * ntiles * 64;
    if (id >= total) return;
    int lane = id & 63;
    int nt = (id >> 6) % ntiles;
    int kt = id / (64 * ntiles);
    int n = nt * 16 + (lane & 15);
    int k0 = kt * 32 + (lane >> 4) * 8;
    const float* src = (k0 < 64) ? (Wtop + k0 * ncols + n) : (Wbot + (k0 - 64) * ncols + n);
    unsigned r[4];
#pragma unroll
    for (int p = 0; p < 4; p++)
        r[p] = packbf(src[(2 * p) * ncols], src[(2 * p + 1) * ncols]);
    out[id] = make_uint4(r[0], r[1], r[2], r[3]);
}

// ---------------- SpMM Chebyshev step, bf16 (unchanged from R4) ----------------
__global__ __launch_bounds__(256) void spmm_step(
        const int* __restrict__ rowptr, const int2* __restrict__ edges,
        const uint4* __restrict__ vin, const uint4* __restrict__ tkm2,
        uint4* __restrict__ tout, const int* __restrict__ kmaxp, int k) {
    if (k > 1 && k > kmaxp[0]) return;
    int tid = threadIdx.x;
    int lane8 = tid & 7;
    int gbase = tid & 56;
    int r = blockIdx.x * 32 + (tid >> 3);
    if (r >= N) return;
    int jb = rowptr[r], je = rowptr[r + 1];
    float a0=0,a1=0,a2=0,a3=0,a4=0,a5=0,a6=0,a7=0;
    for (int j0 = jb; j0 < je; j0 += 8) {
        int jj = j0 + lane8;
        int myc = 0; float myw = 0.f;
        if (jj < je) { int2 e = edges[jj]; myc = e.x; myw = __int_as_float(e.y); }
#pragma unroll
        for (int i = 0; i < 8; i++) {
            int c = __shfl(myc, gbase + i, 64);
            float w = __shfl(myw, gbase + i, 64);
            uint4 v = vin[c * 8 + lane8];
            a0 = fmaf(w, bf2f(v.x & 0xFFFFu), a0);
            a1 = fmaf(w, bf2f(v.x >> 16),     a1);
            a2 = fmaf(w, bf2f(v.y & 0xFFFFu), a2);
            a3 = fmaf(w, bf2f(v.y >> 16),     a3);
            a4 = fmaf(w, bf2f(v.z & 0xFFFFu), a4);
            a5 = fmaf(w, bf2f(v.z >> 16),     a5);
            a6 = fmaf(w, bf2f(v.w & 0xFFFFu), a6);
            a7 = fmaf(w, bf2f(v.w >> 16),     a7);
        }
    }
    float s0=-a0,s1=-a1,s2=-a2,s3=-a3,s4=-a4,s5=-a5,s6=-a6,s7=-a7;
    int idx = r * 8 + lane8;
    if (k >= 2) {
        uint4 tm = tkm2[idx];
        s0 = 2.f*s0 - bf2f(tm.x & 0xFFFFu);
        s1 = 2.f*s1 - bf2f(tm.x >> 16);
        s2 = 2.f*s2 - bf2f(tm.y & 0xFFFFu);
        s3 = 2.f*s3 - bf2f(tm.y >> 16);
        s4 = 2.f*s4 - bf2f(tm.z & 0xFFFFu);
        s5 = 2.f*s5 - bf2f(tm.z >> 16);
        s6 = 2.f*s6 - bf2f(tm.w & 0xFFFFu);
        s7 = 2.f*s7 - bf2f(tm.w >> 16);
    }
    uint4 o;
    o.x = packbf(s0, s1); o.y = packbf(s2, s3);
    o.z = packbf(s4, s5); o.w = packbf(s6, s7);
    tout[idx] = o;
}

// ---------------- MFMA matmul: hidden = relu([base|heat] @ Bfrag), 64 cols ------
// A-tile 64x128 bf16 in LDS (heat fused in staging). 4 waves x (4 n-tiles x 4 k).
__global__ __launch_bounds__(256) void matmul_hidden(
        const unsigned short* __restrict__ basebf, const unsigned short* __restrict__ Tall,
        int nslots, const float* __restrict__ coeffs, const int* __restrict__ kmaxp,
        const uint4* __restrict__ Wfrag, unsigned short* __restrict__ hidbf) {
    __shared__ __align__(16) unsigned short At[64][136];   // pad 8 -> row stride 272B
    int tid = threadIdx.x;
    int row0 = blockIdx.x * 64;
    int kmax = kmaxp[0]; if (kmax > KCHEB - 1) kmax = KCHEB - 1;
    float c0 = coeffs[0];
    for (int u = tid; u < 1024; u += 256) {
        int rr = u >> 4, seg = u & 15;
        int r = row0 + rr;
        uint4 val = make_uint4(0, 0, 0, 0);
        int col;
        if (seg < 8) {
            col = seg * 8;
            if (r < N) val = *(const uint4*)(basebf + (size_t)r * 64 + seg * 8);
        } else {
            int s = seg - 8;
            col = 64 + s * 8;
            if (r < N) {
                uint4 xv = *(const uint4*)(basebf + (size_t)r * 64 + s * 8);
                float h[8], f[8];
                unpack8(xv, f);
#pragma unroll
                for (int q = 0; q < 8; q++) h[q] = c0 * f[q];
                for (int j = 1; j <= kmax; j++) {
                    const unsigned short* Tj = Tall + (size_t)((j - 1) % nslots) * N64;
                    uint4 tv = *(const uint4*)(Tj + (size_t)r * 64 + s * 8);
                    float g[8];
                    unpack8(tv, g);
                    float cj = coeffs[j];
#pragma unroll
                    for (int q = 0; q < 8; q++) h[q] = fmaf(cj, g[q], h[q]);
                }
                val = pack8(h);
            }
        }
        *(uint4*)&At[rr][col] = val;
    }
    __syncthreads();
    int wv = tid >> 6, lane = tid & 63;
    int m0 = wv * 16;
    short8 afr[4];
#pragma unroll
    for (int kt = 0; kt < 4; kt++)
        afr[kt] = *(const short8*)&At[m0 + (lane & 15)][kt * 32 + (lane >> 4) * 8];
    f32x4 acc[4];
#pragma unroll
    for (int nt = 0; nt < 4; nt++) acc[nt] = (f32x4){0.f, 0.f, 0.f, 0.f};
#pragma unroll
    for (int nt = 0; nt < 4; nt++) {
#pragma unroll
        for (int kt = 0; kt < 4; kt++) {
            short8 bfr = *(const short8*)&Wfrag[kt * 256 + nt * 64 + lane];
            acc[nt] = __builtin_amdgcn_mfma_f32_16x16x32_bf16(afr[kt], bfr, acc[nt], 0, 0, 0);
        }
    }
#pragma unroll
    for (int nt = 0; nt < 4; nt++) {
#pragma unroll
        for (int i = 0; i < 4; i++) {
            int r = row0 + m0 + (lane >> 4) * 4 + i;
            if (r < N)
                hidbf[(size_t)r * 64 + nt * 16 + (lane & 15)] =
                    (unsigned short)f2bf(fmaxf(acc[nt][i], 0.f));
        }
    }
}

// ---------------- MFMA matmul + log_softmax: out = lsm([hid|heat2] @ Bfrag) ----
__global__ __launch_bounds__(256) void matmul_out(
        const unsigned short* __restrict__ basebf, const unsigned short* __restrict__ Tall,
        int nslots, const float* __restrict__ coeffs, const int* __restrict__ kmaxp,
        const uint4* __restrict__ Wfrag, float* __restrict__ out) {
    __shared__ __align__(16) unsigned short At[64][136];
    int tid = threadIdx.x;
    int row0 = blockIdx.x * 64;
    int kmax = kmaxp[0]; if (kmax > KCHEB - 1) kmax = KCHEB - 1;
    float c0 = coeffs[0];
    for (int u = tid; u < 1024; u += 256) {
        int rr = u >> 4, seg = u & 15;
        int r = row0 + rr;
        uint4 val = make_uint4(0, 0, 0, 0);
        int col;
        if (seg < 8) {
            col = seg * 8;
            if (r < N) val = *(const uint4*)(basebf + (size_t)r * 64 + seg * 8);
        } else {
            int s = seg - 8;
            col = 64 + s * 8;
            if (r < N) {
                uint4 xv = *(const uint4*)(basebf + (size_t)r * 64 + s * 8);
                float h[8], f[8];
                unpack8(xv, f);
#pragma unroll
                for (int q = 0; q < 8; q++) h[q] = c0 * f[q];
                for (int j = 1; j <= kmax; j++) {
                    const unsigned short* Tj = Tall + (size_t)((j - 1) % nslots) * N64;
                    uint4 tv = *(const uint4*)(Tj + (size_t)r * 64 + s * 8);
                    float g[8];
                    unpack8(tv, g);
                    float cj = coeffs[j];
#pragma unroll
                    for (int q = 0; q < 8; q++) h[q] = fmaf(cj, g[q], h[q]);
                }
                val = pack8(h);
            }
        }
        *(uint4*)&At[rr][col] = val;
    }
    __syncthreads();
    int wv = tid >> 6, lane = tid & 63;
    int m0 = wv * 16;
    short8 afr[4];
#pragma unroll
    for (int kt = 0; kt < 4; kt++)
        afr[kt] = *(const short8*)&At[m0 + (lane & 15)][kt * 32 + (lane >> 4) * 8];
    f32x4 acc[2];
    acc[0] = (f32x4){0.f, 0.f, 0.f, 0.f};
    acc[1] = (f32x4){0.f, 0.f, 0.f, 0.f};
#pragma unroll
    for (int nt = 0; nt < 2; nt++) {
#pragma unroll
        for (int kt = 0; kt < 4; kt++) {
            short8 bfr = *(const short8*)&Wfrag[kt * 128 + nt * 64 + lane];
            acc[nt] = __builtin_amdgcn_mfma_f32_16x16x32_bf16(afr[kt], bfr, acc[nt], 0, 0, 0);
        }
    }
#pragma unroll
    for (int i = 0; i < 4; i++) {
        float f0 = acc[0][i], f1 = acc[1][i];
        float m = fmaxf(f0, f1);
#pragma unroll
        for (int o = 1; o < 16; o <<= 1) m = fmaxf(m, __shfl_xor(m, o, 64));
        float s = expf(f0 - m) + expf(f1 - m);
#pragma unroll
        for (int o = 1; o < 16; o <<= 1) s += __shfl_xor(s, o, 64);
        float ls = m + logf(s);
        int r = row0 + m0 + (lane >> 4) * 4 + i;
        if (r < N) {
            out[(size_t)r * 32 + (lane & 15)] = f0 - ls;
            out[(size_t)r * 32 + 16 + (lane & 15)] = f1 - ls;
        }
    }
}

extern "C" void kernel_launch(void* const* d_in, const int* in_sizes, int n_in,
                              void* d_out, int out_size, void* d_ws, size_t ws_size,
                              hipStream_t stream) {
    const float* x   = (const float*)d_in[0];
    const int*   ei  = (const int*)d_in[1];
    const float* Wd  = (const float*)d_in[2];
    const float* Wh1 = (const float*)d_in[3];
    const float* Whd = (const float*)d_in[4];
    const float* Wh2 = (const float*)d_in[5];
    const float* tp  = (const float*)d_in[6];
    const int* row = ei;
    const int* col = ei + E;

    size_t off = 0;
    auto alloc = [&](size_t bytes) -> void* {
        void* p = (char*)d_ws + off;
        off += (bytes + 255) & ~(size_t)255;
        return p;
    };
    int*   deg      = (int*)alloc((size_t)N * 4);
    int*   rowptr   = (int*)alloc((size_t)(N + 1) * 4);
    int*   fillc    = (int*)alloc((size_t)N * 4);
    float* dinv     = (float*)alloc((size_t)N * 4);
    float* coeffs   = (float*)alloc(KCHEB * 4);
    int*   kmaxp    = (int*)alloc(4);
    int*   blocksum = (int*)alloc(SCAN_BLOCKS * 4);
    int*   blockoff = (int*)alloc(SCAN_BLOCKS * 4);
    int2*  edges    = (int2*)alloc((size_t)E * 8);
    unsigned short* xbf   = (unsigned short*)alloc(N64 * 2);
    unsigned short* hidbf = (unsigned short*)alloc(N64 * 2);
    uint4* Wfrag1   = (uint4*)alloc(1024 * 16);
    uint4* Wfrag2   = (uint4*)alloc(512 * 16);
    size_t tbytes = ((N64 * 2 + 255) & ~(size_t)255);
    int nslots = (int)((ws_size - off) / tbytes);
    if (nslots > KCHEB - 1) nslots = KCHEB - 1;
    if (nslots < 1) nslots = 1;
    unsigned short* Tall = (unsigned short*)alloc((size_t)nslots * tbytes);
    auto Tslot = [&](int k) -> unsigned short* {
        return (unsigned short*)((char*)Tall + (size_t)((k - 1) % nslots) * tbytes);
    };

    hipMemsetAsync(deg, 0, (size_t)N * 4, stream);
    hipMemsetAsync(fillc, 0, (size_t)N * 4, stream);

    count_deg<<<(E + 255) / 256, 256, 0, stream>>>(row, deg);
    scan_a<<<SCAN_BLOCKS, 256, 0, stream>>>(deg, blocksum);
    scan_b<<<1, 256, 0, stream>>>(blocksum, blockoff, rowptr);
    scan_c<<<SCAN_BLOCKS, 256, 0, stream>>>(deg, blockoff, rowptr);
    compute_dinv<<<(N + 255) / 256, 256, 0, stream>>>(rowptr, dinv);
    compute_coeffs<<<1, 64, 0, stream>>>(tp, coeffs, kmaxp);
    fill_csr<<<(E + 255) / 256, 256, 0, stream>>>(row, col, rowptr, fillc, dinv, edges);
    convert_bf16<<<(int)(N64 / 8 + 255) / 256, 256, 0, stream>>>((const float4*)x, (uint4*)xbf);
    pack_wfrag<<<4, 256, 0, stream>>>(Wd, Wh1, 64, Wfrag1);
    pack_wfrag<<<2, 256, 0, stream>>>(Whd, Wh2, 32, Wfrag2);

    const int spmm_grid = (N + 31) / 32;
    const int mm_grid = (N + 63) / 64;

    // ---- heat phase 1: base = x (bf16) ----
    for (int k = 1; k < KCHEB; k++) {
        const uint4* vin = (k == 1) ? (const uint4*)xbf : (const uint4*)Tslot(k - 1);
        const uint4* tm2 = (k <= 2) ? (const uint4*)xbf : (const uint4*)Tslot(k - 2);
        spmm_step<<<spmm_grid, 256, 0, stream>>>(rowptr, edges, vin, tm2,
                                                 (uint4*)Tslot(k), kmaxp, k);
    }
    matmul_hidden<<<mm_grid, 256, 0, stream>>>(xbf, Tall, nslots, coeffs, kmaxp, Wfrag1, hidbf);

    // ---- heat phase 2: base = hidden (bf16) ----
    for (int k = 1; k < KCHEB; k++) {
        const uint4* vin = (k == 1) ? (const uint4*)hidbf : (const uint4*)Tslot(k - 1);
        const uint4* tm2 = (k <= 2) ? (const uint4*)hidbf : (const uint4*)Tslot(k - 2);
        spmm_step<<<spmm_grid, 256, 0, stream>>>(rowptr, edges, vin, tm2,
                                                 (uint4*)Tslot(k), kmaxp, k);
    }
    matmul_out<<<mm_grid, 256, 0, stream>>>(hidbf, Tall, nslots, coeffs, kmaxp, Wfrag2, (float*)d_out);
}